// Round 12
// baseline (73.307 us; speedup 1.0000x reference)
//
#include <hip/hip_runtime.h>
#include <hip/hip_bf16.h>

typedef __attribute__((ext_vector_type(8))) short short8;
typedef __attribute__((ext_vector_type(4))) float f32x4;
typedef __attribute__((ext_vector_type(16))) float f32x16;
typedef __attribute__((ext_vector_type(2))) int int2v;

#define N_TOK 8192
#define D_HALF 64
#define D_FULL 128
#define QB 128                     // q rows per block (4 sub-tiles of 32)
#define KQ 2048                    // keys per block (k-split 4)
#define CHUNK 128                  // keys staged per chunk (32KB K + 32KB V)
#define NCH (KQ / CHUNK)           // 16
#define OSTR 132
#define THR 8.0f                   // log2-domain: P <= 2^8 = 256
#define RSC 1.2011224087864498f    // sqrt(log2(e)): scores scale by log2(e)

// Fragment-major layouts (short8 = 16B units):
//   Kf8[(panel*16 + ks*2 + hi)*32 + li]  = K[panel*32+li][ks*16+8*hi .. +8]  (x RSC)
//   Vf8[(kc*4 + dblk)*64 + hi*32 + li]   = V^T[dblk*32+li][kc*16+8*hi .. +8] (raw)
__global__ __launch_bounds__(256) void precompute_kernel(
    const float* __restrict__ mag, const float* __restrict__ phase,
    __hip_bfloat16* __restrict__ Kf, __hip_bfloat16* __restrict__ Vf)
{
    int idx = blockIdx.x * 256 + threadIdx.x;
    if (idx >= N_TOK * D_HALF) return;
    int n = idx >> 6, d0 = idx & 63;
    float m = mag[idx], p = phase[idx];
    float s, c;
    sincosf(p, &s, &c);
    {
        float val[2] = { m * c * RSC, m * s * RSC };
        #pragma unroll
        for (int h = 0; h < 2; ++h) {
            int dc = d0 + 64 * h;
            int off = ((n >> 5) * 16 + (dc >> 4) * 2 + ((dc >> 3) & 1)) * 256
                      + (n & 31) * 8 + (dc & 7);
            Kf[off] = __float2bfloat16(val[h]);
        }
    }
    {
        float val[2] = { m, p };
        #pragma unroll
        for (int h = 0; h < 2; ++h) {
            int dv = d0 + 64 * h;
            int off = ((n >> 4) * 4 + (dv >> 5)) * 512 + ((n >> 3) & 1) * 256
                      + (dv & 31) * 8 + (n & 7);
            Vf[off] = __float2bfloat16(val[h]);
        }
    }
}

static __device__ __forceinline__ unsigned bfpair(float lo, float hi)
{
    __hip_bfloat16 l = __float2bfloat16(lo), h = __float2bfloat16(hi);
    unsigned short ul = *reinterpret_cast<unsigned short*>(&l);
    unsigned short uh = *reinterpret_cast<unsigned short*>(&h);
    return (unsigned)ul | ((unsigned)uh << 16);
}

// 512 thr = 8 waves = (qh 0..3) x (kp 0..1); wave handles panels {kp, kp+2}.
// Counted-vmcnt pipeline (R11) + panel-interleaved body: QK(p0);QK(p1);
// SM(p0);PV(p0);SM(p1);PV(p1) so softmax VALU overlaps MFMA execution
// (R11 counters: MFMA 24% + VALU 33% + 43% both-idle from serial phases).
__global__ __launch_bounds__(512, 2) void attn_kernel(
    const short8* __restrict__ Kf8, const short8* __restrict__ Vf8,
    float* __restrict__ Opart, float* __restrict__ Mp, float* __restrict__ Sp)
{
    __shared__ __align__(16) char smem[131072];  // 2 x (K 32KB | V 32KB)

    const int tid  = threadIdx.x;
    const int wid  = tid >> 6;     // 0..7
    const int lane = tid & 63;
    const int li   = lane & 31;
    const int hi   = lane >> 5;
    const int qh   = wid >> 1;     // q sub-tile 0..3
    const int kp   = wid & 1;      // key panel group

    const int bid  = blockIdx.x;
    const int qt   = bid >> 2;     // 0..63
    const int kq   = bid & 3;      // key quarter
    const int rot  = bid & (NCH - 1);

    float (*O_lds)[32][OSTR] = (float (*)[32][OSTR])smem;   // merge reuse
    float* ms_base = (float*)(smem + 67584);                // [4][2][32]
    auto msm = [&](int slot, int which) -> float* { return ms_base + (slot * 2 + which) * 32; };

    auto stageKV = [&](int ck, char* lbase) {
        const char* gk = (const char*)(Kf8 + (size_t)ck * 2048);
        const char* gv = (const char*)(Vf8 + (size_t)ck * 2048);
        #pragma unroll
        for (int j = 0; j < 4; ++j)
            __builtin_amdgcn_global_load_lds(
                (const __attribute__((address_space(1))) void*)(gk + j * 8192 + tid * 16),
                (__attribute__((address_space(3))) void*)(lbase + j * 8192 + tid * 16),
                16, 0, 0);
        #pragma unroll
        for (int j = 0; j < 4; ++j)
            __builtin_amdgcn_global_load_lds(
                (const __attribute__((address_space(1))) void*)(gv + j * 8192 + tid * 16),
                (__attribute__((address_space(3))) void*)(lbase + 32768 + j * 8192 + tid * 16),
                16, 0, 0);
    };
    auto ck_of = [&](int t) { return kq * NCH + ((t + rot) & (NCH - 1)); };

    // Q fragments FIRST (oldest in vmcnt queue, so counted waits stay exact)
    short8 bq[8];
    {
        const short8* qp = Kf8 + (size_t)(qt * 4 + qh) * 512;
        #pragma unroll
        for (int ks = 0; ks < 8; ++ks)
            bq[ks] = qp[(ks * 2 + hi) * 32 + li];
    }

    f32x16 acc[4];
    #pragma unroll
    for (int d = 0; d < 4; ++d) acc[d] = (f32x16)(0.0f);
    float mrow = -3.0e38f, srow = 0.0f;

    // softmax on one panel's scores (log2 domain, exp2 direct)
    auto softmax = [&](f32x16& st) {
        float mx[8];
        #pragma unroll
        for (int r = 0; r < 8; ++r) mx[r] = fmaxf(st[r], st[r + 8]);
        float ma = fmaxf(fmaxf(mx[0], mx[1]), mx[2]);     // v_max3
        float mb = fmaxf(fmaxf(mx[3], mx[4]), mx[5]);
        float mc = fmaxf(mx[6], mx[7]);
        float mm = fmaxf(fmaxf(ma, mb), mc);
        float pmax = fmaxf(mm, __shfl_xor(mm, 32));
        if (!__all(pmax - mrow <= THR)) {                 // defer-max
            float mn  = fmaxf(mrow, pmax);
            float scl = exp2f(mrow - mn);
            srow *= scl;
            #pragma unroll
            for (int d = 0; d < 4; ++d)
                #pragma unroll
                for (int r = 0; r < 16; ++r) acc[d][r] *= scl;
            mrow = mn;
        }
        #pragma unroll
        for (int r = 0; r < 16; ++r) st[r] = exp2f(st[r] - mrow);
        float sm[8];
        #pragma unroll
        for (int r = 0; r < 8; ++r) sm[r] = st[r] + st[r + 8];
        float sa = (sm[0] + sm[1]) + (sm[2] + sm[3]);
        float sb = (sm[4] + sm[5]) + (sm[6] + sm[7]);
        float ss = sa + sb;
        srow += ss + __shfl_xor(ss, 32);
    };

    // PV for one panel: pack P -> bf16 fragments, 8 MFMA into acc
    auto pv = [&](const f32x16& st, int panel, const short8* ldsV) {
        #pragma unroll
        for (int c = 0; c < 2; ++c) {
            const int b = 8 * c;
            unsigned a0 = bfpair(st[b + 0], st[b + 1]);
            unsigned a1 = bfpair(st[b + 2], st[b + 3]);
            unsigned b0 = bfpair(st[b + 4], st[b + 5]);
            unsigned b1 = bfpair(st[b + 6], st[b + 7]);
            int2v r0 = __builtin_amdgcn_permlane32_swap((int)a0, (int)b0, false, false);
            int2v r1 = __builtin_amdgcn_permlane32_swap((int)a1, (int)b1, false, false);
            union { int w[4]; short8 v; } u;
            u.w[0] = r0[0]; u.w[1] = r1[0]; u.w[2] = r0[1]; u.w[3] = r1[1];

            const short8* vp = ldsV + (panel * 2 + c) * 256 + hi * 32 + li;
            __builtin_amdgcn_s_setprio(1);
            #pragma unroll
            for (int d = 0; d < 4; ++d) {
                short8 vf = vp[d * 64];
                acc[d] = __builtin_amdgcn_mfma_f32_32x32x16_bf16(vf, u.v, acc[d], 0, 0, 0);
            }
            __builtin_amdgcn_s_setprio(0);
        }
    };

    stageKV(ck_of(0), smem);
    stageKV(ck_of(1), smem + 65536);
    asm volatile("s_waitcnt vmcnt(8)");     // S(0) complete, S(1) in flight
    __builtin_amdgcn_s_barrier();

    for (int t = 0; t < NCH; ++t) {
        char* base = smem + (t & 1) * 65536;
        const short8* ldsK = (const short8*)base;
        const short8* ldsV = (const short8*)(base + 32768);
        const int p0 = kp, p1 = kp + 2;

        // ---- QK^T both panels back-to-back (fill the MFMA pipe) ----
        f32x16 st0 = (f32x16)(0.0f), st1 = (f32x16)(0.0f);
        __builtin_amdgcn_s_setprio(1);
        #pragma unroll
        for (int ks = 0; ks < 8; ++ks) {
            short8 kf = ldsK[p0 * 512 + (ks * 2 + hi) * 32 + li];
            st0 = __builtin_amdgcn_mfma_f32_32x32x16_bf16(kf, bq[ks], st0, 0, 0, 0);
        }
        #pragma unroll
        for (int ks = 0; ks < 8; ++ks) {
            short8 kf = ldsK[p1 * 512 + (ks * 2 + hi) * 32 + li];
            st1 = __builtin_amdgcn_mfma_f32_32x32x16_bf16(kf, bq[ks], st1, 0, 0, 0);
        }
        __builtin_amdgcn_s_setprio(0);

        // ---- interleaved: SM0 overlaps QK1 exec; SM1 overlaps PV0 exec ----
        softmax(st0);
        pv(st0, p0, ldsV);
        softmax(st1);
        pv(st1, p1, ldsV);

        __builtin_amdgcn_s_barrier();            // all waves done reading buf
        if (t + 2 < NCH) {
            stageKV(ck_of(t + 2), base);         // refill this buffer
            asm volatile("s_waitcnt vmcnt(8)");  // S(t+1) landed, S(t+2) flying
        } else {
            asm volatile("s_waitcnt vmcnt(0)");  // epilogue drain
        }
        __builtin_amdgcn_s_barrier();            // next buffer ready for all
    }

    // ---- in-block merge over kp (2 partials per qh) ----
    auto store_partial = [&](int slot) {
        #pragma unroll
        for (int d = 0; d < 4; ++d)
            #pragma unroll
            for (int rr = 0; rr < 4; ++rr) {
                f32x4 v;
                #pragma unroll
                for (int j = 0; j < 4; ++j) v[j] = acc[d][4 * rr + j];
                *reinterpret_cast<f32x4*>(&O_lds[slot][li][d * 32 + 8 * rr + 4 * hi]) = v;
            }
        if (hi == 0) { msm(slot, 0)[li] = mrow; msm(slot, 1)[li] = srow; }
    };
    auto merge_partial = [&](int slot) {
        float mb = msm(slot, 0)[li], sb = msm(slot, 1)[li];
        float M  = fmaxf(mrow, mb);
        float ea = exp2f(mrow - M), eb = exp2f(mb - M);
        srow = srow * ea + sb * eb;
        mrow = M;
        #pragma unroll
        for (int d = 0; d < 4; ++d)
            #pragma unroll
            for (int rr = 0; rr < 4; ++rr) {
                f32x4 v = *reinterpret_cast<const f32x4*>(&O_lds[slot][li][d * 32 + 8 * rr + 4 * hi]);
                #pragma unroll
                for (int j = 0; j < 4; ++j)
                    acc[d][4 * rr + j] = acc[d][4 * rr + j] * ea + v[j] * eb;
            }
    };

    __syncthreads();                         // staging dead; reuse as merge space
    if (kp == 1) store_partial(qh);
    __syncthreads();
    if (kp == 0) merge_partial(qh);
    __syncthreads();
    if (kp == 0) store_partial(qh);
    __syncthreads();

    // ---- write UNNORMALIZED per-block partial (128 q x 128 d) + (M,S) ----
    #pragma unroll
    for (int u0 = 0; u0 < 4; ++u0) {
        int u  = tid + u0 * 512;           // 0..2047
        int q  = u >> 4;                   // 0..127
        int dg = (u & 15) * 8;             // 0..120
        int grp = q >> 5, qq = q & 31;
        f32x4 o0 = *reinterpret_cast<const f32x4*>(&O_lds[grp][qq][dg]);
        f32x4 o1 = *reinterpret_cast<const f32x4*>(&O_lds[grp][qq][dg + 4]);
        size_t pidx = (size_t)bid * QB + q;
        *reinterpret_cast<f32x4*>(&Opart[pidx * D_FULL + dg])     = o0;
        *reinterpret_cast<f32x4*>(&Opart[pidx * D_FULL + dg + 4]) = o1;
        if (dg == 0) { Mp[pidx] = msm(grp, 0)[qq]; Sp[pidx] = msm(grp, 1)[qq]; }
    }
}

// combine the four k-quarter partials per q-row and write final output
__global__ __launch_bounds__(256) void merge4_kernel(
    const float* __restrict__ Opart, const float* __restrict__ Mp,
    const float* __restrict__ Sp, float* __restrict__ out)
{
    int i   = blockIdx.x * 256 + threadIdx.x;   // 262144 total, 4 floats each
    int row = i >> 5;                           // 0..8191
    int dg  = (i & 31) * 4;                     // 0..124
    int qt  = row >> 7, qq = row & 127;
    size_t pidx[4];
    float m[4], s[4];
    #pragma unroll
    for (int k = 0; k < 4; ++k) {
        pidx[k] = (size_t)(qt * 4 + k) * QB + qq;
        m[k] = Mp[pidx[k]];
        s[k] = Sp[pidx[k]];
    }
    float M = fmaxf(fmaxf(m[0], m[1]), fmaxf(m[2], m[3]));
    float e[4], S = 0.0f;
    #pragma unroll
    for (int k = 0; k < 4; ++k) { e[k] = exp2f(m[k] - M); S += s[k] * e[k]; }
    float inv = 1.0f / S;
    f32x4 o = (f32x4)(0.0f);
    #pragma unroll
    for (int k = 0; k < 4; ++k) {
        f32x4 a = *reinterpret_cast<const f32x4*>(&Opart[pidx[k] * D_FULL + dg]);
        #pragma unroll
        for (int j = 0; j < 4; ++j) o[j] += a[j] * e[k];
    }
    #pragma unroll
    for (int j = 0; j < 4; ++j) o[j] *= inv;
    float* dst = (dg < D_HALF)
        ? out + (size_t)row * D_HALF + dg
        : out + (size_t)N_TOK * D_HALF + (size_t)row * D_HALF + (dg - D_HALF);
    *reinterpret_cast<f32x4*>(dst) = o;
}

extern "C" void kernel_launch(void* const* d_in, const int* in_sizes, int n_in,
                              void* d_out, int out_size, void* d_ws, size_t ws_size,
                              hipStream_t stream)
{
    const float* mag   = (const float*)d_in[0];
    const float* phase = (const float*)d_in[1];
    float* out = (float*)d_out;

    char* ws = (char*)d_ws;
    __hip_bfloat16* Kf = (__hip_bfloat16*)ws;                    // 2 MB
    __hip_bfloat16* Vf = Kf + (size_t)N_TOK * D_FULL;            // 2 MB
    float* Opart = (float*)(ws + 4u * 1024 * 1024);              // 16 MB
    float* Mp    = (float*)(ws + 20u * 1024 * 1024);             // 128 KB
    float* Sp    = Mp + 32768;                                   // 128 KB

    precompute_kernel<<<(N_TOK * D_HALF + 255) / 256, 256, 0, stream>>>(mag, phase, Kf, Vf);
    attn_kernel<<<256, 512, 0, stream>>>((const short8*)Kf, (const short8*)Vf, Opart, Mp, Sp);
    merge4_kernel<<<1024, 256, 0, stream>>>(Opart, Mp, Sp, out);
}

// Round 14
// 66.262 us; speedup vs baseline: 1.1063x; 1.1063x over previous
//
#include <hip/hip_runtime.h>
#include <hip/hip_bf16.h>

typedef __attribute__((ext_vector_type(8))) short short8;
typedef __attribute__((ext_vector_type(4))) float f32x4;
typedef __attribute__((ext_vector_type(16))) float f32x16;
typedef __attribute__((ext_vector_type(2))) int int2v;

#define N_TOK 8192
#define D_HALF 64
#define D_FULL 128
#define QB 128                     // q rows per block (4 sub-tiles of 32)
#define KQ 2048                    // keys per block (k-split 4)
#define CHUNK 128                  // keys staged per chunk (32KB K + 32KB V)
#define NCH (KQ / CHUNK)           // 16
#define OSTR 132
#define RSC 1.2011224087864498f    // sqrt(log2(e)): scores arrive in log2 domain
#define MFIX 94.0f                 // fixed softmax max: > 64*log2(e)=92.33 bound

// Fragment-major layouts (short8 = 16B units):
//   Kf8[(panel*16 + ks*2 + hi)*32 + li]  = K[panel*32+li][ks*16+8*hi .. +8]  (x RSC)
//   Vf8[(kc*4 + dblk)*64 + hi*32 + li]   = V^T[dblk*32+li][kc*16+8*hi .. +8] (raw)
__global__ __launch_bounds__(256) void precompute_kernel(
    const float* __restrict__ mag, const float* __restrict__ phase,
    __hip_bfloat16* __restrict__ Kf, __hip_bfloat16* __restrict__ Vf)
{
    int idx = blockIdx.x * 256 + threadIdx.x;
    if (idx >= N_TOK * D_HALF) return;
    int n = idx >> 6, d0 = idx & 63;
    float m = mag[idx], p = phase[idx];
    float s, c;
    sincosf(p, &s, &c);
    {
        float val[2] = { m * c * RSC, m * s * RSC };
        #pragma unroll
        for (int h = 0; h < 2; ++h) {
            int dc = d0 + 64 * h;
            int off = ((n >> 5) * 16 + (dc >> 4) * 2 + ((dc >> 3) & 1)) * 256
                      + (n & 31) * 8 + (dc & 7);
            Kf[off] = __float2bfloat16(val[h]);
        }
    }
    {
        float val[2] = { m, p };
        #pragma unroll
        for (int h = 0; h < 2; ++h) {
            int dv = d0 + 64 * h;
            int off = ((n >> 4) * 4 + (dv >> 5)) * 512 + ((n >> 3) & 1) * 256
                      + (dv & 31) * 8 + (n & 7);
            Vf[off] = __float2bfloat16(val[h]);
        }
    }
}

// pack two f32 into one bf16x2 word (lo=a, hi=b) -- single v_cvt_pk_bf16_f32
static __device__ __forceinline__ unsigned cvtpk(float a, float b)
{
    unsigned r;
    asm("v_cvt_pk_bf16_f32 %0, %1, %2" : "=v"(r) : "v"(a), "v"(b));
    return r;
}

// R11 structure exactly (counted-vmcnt double-buffer DMA pipeline), with
// FIXED-MAX softmax: scores bounded by 64*log2e<94 in log2 domain, so
// P = exp2(s - 94) needs no running max, no defer branch, no rescale, and
// the subtract folds into the MFMA C-initializer. Merges become pure sums.
// R13 bug fixed: final Sp write must read the MERGED sum from LDS
// (sslot(grp)[qq]), not the thread's private srow.
__global__ __launch_bounds__(512, 2) void attn_kernel(
    const short8* __restrict__ Kf8, const short8* __restrict__ Vf8,
    float* __restrict__ Opart, float* __restrict__ Sp)
{
    __shared__ __align__(16) char smem[131072];  // 2 x (K 32KB | V 32KB)

    const int tid  = threadIdx.x;
    const int wid  = tid >> 6;     // 0..7
    const int lane = tid & 63;
    const int li   = lane & 31;
    const int hi   = lane >> 5;
    const int qh   = wid >> 1;     // q sub-tile 0..3
    const int kp   = wid & 1;      // key panel group

    const int bid  = blockIdx.x;
    const int qt   = bid >> 2;     // 0..63
    const int kq   = bid & 3;      // key quarter
    const int rot  = bid & (NCH - 1);

    float (*O_lds)[32][OSTR] = (float (*)[32][OSTR])smem;   // merge reuse
    float* s_base = (float*)(smem + 67584);                 // [4][32]
    auto sslot = [&](int slot) -> float* { return s_base + slot * 32; };

    auto stageKV = [&](int ck, char* lbase) {
        const char* gk = (const char*)(Kf8 + (size_t)ck * 2048);
        const char* gv = (const char*)(Vf8 + (size_t)ck * 2048);
        #pragma unroll
        for (int j = 0; j < 4; ++j)
            __builtin_amdgcn_global_load_lds(
                (const __attribute__((address_space(1))) void*)(gk + j * 8192 + tid * 16),
                (__attribute__((address_space(3))) void*)(lbase + j * 8192 + tid * 16),
                16, 0, 0);
        #pragma unroll
        for (int j = 0; j < 4; ++j)
            __builtin_amdgcn_global_load_lds(
                (const __attribute__((address_space(1))) void*)(gv + j * 8192 + tid * 16),
                (__attribute__((address_space(3))) void*)(lbase + 32768 + j * 8192 + tid * 16),
                16, 0, 0);
    };
    auto ck_of = [&](int t) { return kq * NCH + ((t + rot) & (NCH - 1)); };

    // Q fragments FIRST (oldest in vmcnt queue, so counted waits stay exact)
    short8 bq[8];
    {
        const short8* qp = Kf8 + (size_t)(qt * 4 + qh) * 512;
        #pragma unroll
        for (int ks = 0; ks < 8; ++ks)
            bq[ks] = qp[(ks * 2 + hi) * 32 + li];
    }

    f32x16 acc[4];
    #pragma unroll
    for (int d = 0; d < 4; ++d) acc[d] = (f32x16)(0.0f);
    float srow = 0.0f;

    stageKV(ck_of(0), smem);
    stageKV(ck_of(1), smem + 65536);
    asm volatile("s_waitcnt vmcnt(8)");     // S(0) complete, S(1) in flight
    __builtin_amdgcn_s_barrier();

    for (int t = 0; t < NCH; ++t) {
        char* base = smem + (t & 1) * 65536;
        const short8* ldsK = (const short8*)base;
        const short8* ldsV = (const short8*)(base + 32768);

        #pragma unroll
        for (int pp = 0; pp < 2; ++pp) {
            const int panel = kp + 2 * pp;

            // ---- S^T = K.Q, C-init = -MFIX folds the softmax subtract ----
            f32x16 st = (f32x16)(-MFIX);
            __builtin_amdgcn_s_setprio(1);
            #pragma unroll
            for (int ks = 0; ks < 8; ++ks) {
                short8 kf = ldsK[panel * 512 + (ks * 2 + hi) * 32 + li];
                st = __builtin_amdgcn_mfma_f32_32x32x16_bf16(kf, bq[ks], st, 0, 0, 0);
            }
            __builtin_amdgcn_s_setprio(0);

            // ---- P = exp2(st); row-sum only (no max machinery) ----
            #pragma unroll
            for (int r = 0; r < 16; ++r) st[r] = exp2f(st[r]);
            float sm[8];
            #pragma unroll
            for (int r = 0; r < 8; ++r) sm[r] = st[r] + st[r + 8];
            float ss = ((sm[0] + sm[1]) + (sm[2] + sm[3]))
                     + ((sm[4] + sm[5]) + (sm[6] + sm[7]));
            srow += ss + __shfl_xor(ss, 32);

            // ---- PV: pack P (cvt_pk) -> permlane repack -> 8 MFMA ----
            #pragma unroll
            for (int c = 0; c < 2; ++c) {
                const int b = 8 * c;
                unsigned a0 = cvtpk(st[b + 0], st[b + 1]);
                unsigned a1 = cvtpk(st[b + 2], st[b + 3]);
                unsigned b0 = cvtpk(st[b + 4], st[b + 5]);
                unsigned b1 = cvtpk(st[b + 6], st[b + 7]);
                int2v r0 = __builtin_amdgcn_permlane32_swap((int)a0, (int)b0, false, false);
                int2v r1 = __builtin_amdgcn_permlane32_swap((int)a1, (int)b1, false, false);
                union { int w[4]; short8 v; } u;
                u.w[0] = r0[0]; u.w[1] = r1[0]; u.w[2] = r0[1]; u.w[3] = r1[1];

                const short8* vp = ldsV + (panel * 2 + c) * 256 + hi * 32 + li;
                __builtin_amdgcn_s_setprio(1);
                #pragma unroll
                for (int d = 0; d < 4; ++d) {
                    short8 vf = vp[d * 64];
                    acc[d] = __builtin_amdgcn_mfma_f32_32x32x16_bf16(vf, u.v, acc[d], 0, 0, 0);
                }
                __builtin_amdgcn_s_setprio(0);
            }
        }

        __builtin_amdgcn_s_barrier();            // all waves done reading buf
        if (t + 2 < NCH) {
            stageKV(ck_of(t + 2), base);         // refill this buffer
            asm volatile("s_waitcnt vmcnt(8)");  // S(t+1) landed, S(t+2) flying
        } else {
            asm volatile("s_waitcnt vmcnt(0)");  // epilogue drain
        }
        __builtin_amdgcn_s_barrier();            // next buffer ready for all
    }

    // ---- in-block merge over kp (pure sums; fixed max everywhere) ----
    auto store_partial = [&](int slot) {
        #pragma unroll
        for (int d = 0; d < 4; ++d)
            #pragma unroll
            for (int rr = 0; rr < 4; ++rr) {
                f32x4 v;
                #pragma unroll
                for (int j = 0; j < 4; ++j) v[j] = acc[d][4 * rr + j];
                *reinterpret_cast<f32x4*>(&O_lds[slot][li][d * 32 + 8 * rr + 4 * hi]) = v;
            }
        if (hi == 0) sslot(slot)[li] = srow;
    };
    auto merge_partial = [&](int slot) {
        srow += sslot(slot)[li];
        #pragma unroll
        for (int d = 0; d < 4; ++d)
            #pragma unroll
            for (int rr = 0; rr < 4; ++rr) {
                f32x4 v = *reinterpret_cast<const f32x4*>(&O_lds[slot][li][d * 32 + 8 * rr + 4 * hi]);
                #pragma unroll
                for (int j = 0; j < 4; ++j)
                    acc[d][4 * rr + j] += v[j];
            }
    };

    __syncthreads();                         // staging dead; reuse as merge space
    if (kp == 1) store_partial(qh);
    __syncthreads();
    if (kp == 0) merge_partial(qh);
    __syncthreads();
    if (kp == 0) store_partial(qh);
    __syncthreads();

    // ---- write UNNORMALIZED per-block partial (128 q x 128 d) + S ----
    #pragma unroll
    for (int u0 = 0; u0 < 4; ++u0) {
        int u  = tid + u0 * 512;           // 0..2047
        int q  = u >> 4;                   // 0..127
        int dg = (u & 15) * 8;             // 0..120
        int grp = q >> 5, qq = q & 31;
        f32x4 o0 = *reinterpret_cast<const f32x4*>(&O_lds[grp][qq][dg]);
        f32x4 o1 = *reinterpret_cast<const f32x4*>(&O_lds[grp][qq][dg + 4]);
        size_t pidx = (size_t)bid * QB + q;
        *reinterpret_cast<f32x4*>(&Opart[pidx * D_FULL + dg])     = o0;
        *reinterpret_cast<f32x4*>(&Opart[pidx * D_FULL + dg + 4]) = o1;
        if (dg == 0) Sp[pidx] = sslot(grp)[qq];   // merged sum from LDS (R13 fix)
    }
}

// combine the four k-quarter partials per q-row (pure sums) and normalize
__global__ __launch_bounds__(256) void merge4_kernel(
    const float* __restrict__ Opart, const float* __restrict__ Sp,
    float* __restrict__ out)
{
    int i   = blockIdx.x * 256 + threadIdx.x;   // 262144 total, 4 floats each
    int row = i >> 5;                           // 0..8191
    int dg  = (i & 31) * 4;                     // 0..124
    int qt  = row >> 7, qq = row & 127;
    size_t pidx[4];
    float S = 0.0f;
    #pragma unroll
    for (int k = 0; k < 4; ++k) {
        pidx[k] = (size_t)(qt * 4 + k) * QB + qq;
        S += Sp[pidx[k]];
    }
    float inv = 1.0f / S;
    f32x4 o = (f32x4)(0.0f);
    #pragma unroll
    for (int k = 0; k < 4; ++k) {
        f32x4 a = *reinterpret_cast<const f32x4*>(&Opart[pidx[k] * D_FULL + dg]);
        #pragma unroll
        for (int j = 0; j < 4; ++j) o[j] += a[j];
    }
    #pragma unroll
    for (int j = 0; j < 4; ++j) o[j] *= inv;
    float* dst = (dg < D_HALF)
        ? out + (size_t)row * D_HALF + dg
        : out + (size_t)N_TOK * D_HALF + (size_t)row * D_HALF + (dg - D_HALF);
    *reinterpret_cast<f32x4*>(dst) = o;
}

extern "C" void kernel_launch(void* const* d_in, const int* in_sizes, int n_in,
                              void* d_out, int out_size, void* d_ws, size_t ws_size,
                              hipStream_t stream)
{
    const float* mag   = (const float*)d_in[0];
    const float* phase = (const float*)d_in[1];
    float* out = (float*)d_out;

    char* ws = (char*)d_ws;
    __hip_bfloat16* Kf = (__hip_bfloat16*)ws;                    // 2 MB
    __hip_bfloat16* Vf = Kf + (size_t)N_TOK * D_FULL;            // 2 MB
    float* Opart = (float*)(ws + 4u * 1024 * 1024);              // 16 MB
    float* Sp    = (float*)(ws + 20u * 1024 * 1024);             // 128 KB

    precompute_kernel<<<(N_TOK * D_HALF + 255) / 256, 256, 0, stream>>>(mag, phase, Kf, Vf);
    attn_kernel<<<256, 512, 0, stream>>>((const short8*)Kf, (const short8*)Vf, Opart, Sp);
    merge4_kernel<<<1024, 256, 0, stream>>>(Opart, Sp, out);
}